// Round 1
// baseline (48.648 us; speedup 1.0000x reference)
//
#include <hip/hip_runtime.h>

#define BB 16
#define NN 128
#define DD 128
#define LL 512
#define FFH 512
#define TANH1 0.76159415595576489f

struct alignas(16) f4arr { float v[4]; };

// ---------------------------------------------------------------------------
// K1: c[b,j] = sum_l tanh(in_obs[b,j,:]Wk[:,l] + Wk_b[l]) * wv_w[640+l]
//             + tanh(1) * wv_w[1152+j]
// grid 256 blocks (8 rows each), 256 threads
// ---------------------------------------------------------------------------
__global__ __launch_bounds__(256) void k1_scores(
    const float* __restrict__ in_obs,
    const float* __restrict__ Wk_w,
    const float* __restrict__ Wk_b,
    const float* __restrict__ wv_w,
    float* __restrict__ c_out)
{
    const int t = threadIdx.x;
    const int row0 = blockIdx.x * 8;          // global row = b*128 + j
    __shared__ float row_lds[8][128];
    __shared__ float red[8][4];

    const float* src = in_obs + row0 * DD;
    #pragma unroll
    for (int i = 0; i < 4; ++i) {
        int idx = t + i * 256;
        row_lds[idx >> 7][idx & 127] = src[idx];
    }
    __syncthreads();

    const int l0 = t, l1 = t + 256;
    float acc0[8], acc1[8];
    #pragma unroll
    for (int r = 0; r < 8; ++r) { acc0[r] = 0.f; acc1[r] = 0.f; }

    for (int d = 0; d < 128; d += 4) {
        f4arr rbuf[8];
        #pragma unroll
        for (int r = 0; r < 8; ++r)
            rbuf[r] = *(const f4arr*)&row_lds[r][d];
        #pragma unroll
        for (int dd = 0; dd < 4; ++dd) {
            const float w0 = Wk_w[(d + dd) * LL + l0];
            const float w1 = Wk_w[(d + dd) * LL + l1];
            #pragma unroll
            for (int r = 0; r < 8; ++r) {
                acc0[r] += rbuf[r].v[dd] * w0;
                acc1[r] += rbuf[r].v[dd] * w1;
            }
        }
    }
    const float kb0 = Wk_b[l0], kb1 = Wk_b[l1];
    const float wv0 = wv_w[640 + l0], wv1 = wv_w[640 + l1];
    float v[8];
    #pragma unroll
    for (int r = 0; r < 8; ++r)
        v[r] = tanhf(acc0[r] + kb0) * wv0 + tanhf(acc1[r] + kb1) * wv1;
    #pragma unroll
    for (int off = 32; off > 0; off >>= 1) {
        #pragma unroll
        for (int r = 0; r < 8; ++r)
            v[r] += __shfl_down(v[r], off, 64);
    }
    const int wave = t >> 6, lane = t & 63;
    if (lane == 0) {
        #pragma unroll
        for (int r = 0; r < 8; ++r) red[r][wave] = v[r];
    }
    __syncthreads();
    if (t < 8) {
        const int row = row0 + t;
        const int j = row & (NN - 1);
        c_out[row] = red[t][0] + red[t][1] + red[t][2] + red[t][3]
                   + TANH1 * wv_w[1152 + j];
    }
}

// ---------------------------------------------------------------------------
// K2: per-block (8 rows of one batch): softmax(c[b,:]) -> attn vector ->
//     LN1 -> FF1(relu) -> FF2 -> LN2 -> out
// grid 256 blocks (b = blk>>4, rows j0..j0+7), 256 threads
// ---------------------------------------------------------------------------
__global__ __launch_bounds__(256) void k2_ffn(
    const float* __restrict__ in_obs,
    const float* __restrict__ c_in,
    const float* __restrict__ g1, const float* __restrict__ b1,
    const float* __restrict__ ff1_w, const float* __restrict__ ff1_b,
    const float* __restrict__ ff2_w, const float* __restrict__ ff2_b,
    const float* __restrict__ g2, const float* __restrict__ b2,
    float* __restrict__ out)
{
    const int t = threadIdx.x;
    const int b = blockIdx.x >> 4;
    const int j0 = (blockIdx.x & 15) * 8;

    __shared__ float wts[128];
    __shared__ float attn[128];
    __shared__ float res_lds[8][128];
    __shared__ float h_lds[8][512];
    __shared__ float ffp[2][8][128];
    __shared__ float sred;

    // ---- softmax over c[b,:]  (weights identical for every row i: the
    //      q-side term is constant along the softmax axis and cancels)
    const float* cb = c_in + b * NN;
    if (t < 64) {
        float m = fmaxf(cb[t], cb[t + 64]);
        #pragma unroll
        for (int off = 32; off > 0; off >>= 1)
            m = fmaxf(m, __shfl_xor(m, off, 64));
        if (t == 0) sred = m;
    }
    __syncthreads();
    const float M = sred;
    if (t < 128) wts[t] = expf(cb[t] - M);
    __syncthreads();
    if (t < 64) {
        float s = wts[t] + wts[t + 64];
        #pragma unroll
        for (int off = 32; off > 0; off >>= 1)
            s += __shfl_xor(s, off, 64);
        if (t == 0) sred = s;
    }
    __syncthreads();
    const float Sinv = 1.f / sred;
    if (t < 128) wts[t] *= Sinv;
    __syncthreads();

    // ---- attn vector: attn[d] = sum_j wts[j] * in_obs[b,j,d]  (per batch)
    {
        const int d = t & 127, half = t >> 7;
        const float* base = in_obs + (b * NN + half * 64) * DD + d;
        float a = 0.f;
        #pragma unroll 4
        for (int j = 0; j < 64; ++j)
            a += wts[half * 64 + j] * base[j * DD];
        ffp[half][0][d] = a;
    }
    __syncthreads();
    if (t < 128) attn[t] = ffp[0][0][t] + ffp[1][0][t];
    __syncthreads();

    const int wave = t >> 6, lane = t & 63;

    // ---- residual + LN1 -> res_lds   (wave w owns rows 2w, 2w+1)
    #pragma unroll
    for (int rr = 0; rr < 2; ++rr) {
        const int r = wave * 2 + rr;
        const int row = b * NN + j0 + r;
        const float x0 = attn[lane] + in_obs[row * DD + lane];
        const float x1 = attn[lane + 64] + in_obs[row * DD + lane + 64];
        float s = x0 + x1;
        #pragma unroll
        for (int off = 32; off > 0; off >>= 1) s += __shfl_xor(s, off, 64);
        const float mu = s * (1.f / 128.f);
        const float d0 = x0 - mu, d1 = x1 - mu;
        float vs = d0 * d0 + d1 * d1;
        #pragma unroll
        for (int off = 32; off > 0; off >>= 1) vs += __shfl_xor(vs, off, 64);
        const float rstd = rsqrtf(vs * (1.f / 128.f) + 1e-5f);
        res_lds[r][lane]      = d0 * rstd * g1[lane]      + b1[lane];
        res_lds[r][lane + 64] = d1 * rstd * g1[lane + 64] + b1[lane + 64];
    }
    __syncthreads();

    // ---- FF1: h = relu(res @ ff1_w + ff1_b), thread owns columns t, t+256
    {
        const int l0 = t, l1 = t + 256;
        float acc0[8], acc1[8];
        #pragma unroll
        for (int r = 0; r < 8; ++r) { acc0[r] = 0.f; acc1[r] = 0.f; }
        for (int d = 0; d < 128; d += 4) {
            f4arr rbuf[8];
            #pragma unroll
            for (int r = 0; r < 8; ++r)
                rbuf[r] = *(const f4arr*)&res_lds[r][d];
            #pragma unroll
            for (int dd = 0; dd < 4; ++dd) {
                const float w0 = ff1_w[(d + dd) * FFH + l0];
                const float w1 = ff1_w[(d + dd) * FFH + l1];
                #pragma unroll
                for (int r = 0; r < 8; ++r) {
                    acc0[r] += rbuf[r].v[dd] * w0;
                    acc1[r] += rbuf[r].v[dd] * w1;
                }
            }
        }
        const float fb0 = ff1_b[l0], fb1 = ff1_b[l1];
        #pragma unroll
        for (int r = 0; r < 8; ++r) {
            h_lds[r][l0] = fmaxf(acc0[r] + fb0, 0.f);
            h_lds[r][l1] = fmaxf(acc1[r] + fb1, 0.f);
        }
    }
    __syncthreads();

    // ---- FF2 partials: thread owns output d = t&127, l-half = t>>7
    {
        const int d = t & 127, half = t >> 7;
        float acc[8];
        #pragma unroll
        for (int r = 0; r < 8; ++r) acc[r] = 0.f;
        const int lbase = half * 256;
        for (int l = lbase; l < lbase + 256; l += 4) {
            f4arr hbuf[8];
            #pragma unroll
            for (int r = 0; r < 8; ++r)
                hbuf[r] = *(const f4arr*)&h_lds[r][l];
            #pragma unroll
            for (int ll = 0; ll < 4; ++ll) {
                const float w = ff2_w[(l + ll) * DD + d];
                #pragma unroll
                for (int r = 0; r < 8; ++r)
                    acc[r] += hbuf[r].v[ll] * w;
            }
        }
        #pragma unroll
        for (int r = 0; r < 8; ++r) ffp[half][r][d] = acc[r];
    }
    __syncthreads();

    // ---- combine halves + bias + residual(in_obs) + LN2 -> out
    #pragma unroll
    for (int rr = 0; rr < 2; ++rr) {
        const int r = wave * 2 + rr;
        const int row = b * NN + j0 + r;
        const float f0 = ffp[0][r][lane] + ffp[1][r][lane]
                       + ff2_b[lane] + in_obs[row * DD + lane];
        const float f1 = ffp[0][r][lane + 64] + ffp[1][r][lane + 64]
                       + ff2_b[lane + 64] + in_obs[row * DD + lane + 64];
        float s = f0 + f1;
        #pragma unroll
        for (int off = 32; off > 0; off >>= 1) s += __shfl_xor(s, off, 64);
        const float mu = s * (1.f / 128.f);
        const float d0 = f0 - mu, d1 = f1 - mu;
        float vs = d0 * d0 + d1 * d1;
        #pragma unroll
        for (int off = 32; off > 0; off >>= 1) vs += __shfl_xor(vs, off, 64);
        const float rstd = rsqrtf(vs * (1.f / 128.f) + 1e-5f);
        out[row * DD + lane]      = d0 * rstd * g2[lane]      + b2[lane];
        out[row * DD + lane + 64] = d1 * rstd * g2[lane + 64] + b2[lane + 64];
    }
}

extern "C" void kernel_launch(void* const* d_in, const int* in_sizes, int n_in,
                              void* d_out, int out_size, void* d_ws, size_t ws_size,
                              hipStream_t stream) {
    const float* in_obs = (const float*)d_in[0];
    // d_in[1] Wq_w, d_in[2] Wq_b, d_in[6] wv_b: dead (cancel in softmax)
    const float* Wk_w  = (const float*)d_in[3];
    const float* Wk_b  = (const float*)d_in[4];
    const float* wv_w  = (const float*)d_in[5];
    const float* g1    = (const float*)d_in[7];
    const float* b1    = (const float*)d_in[8];
    const float* ff1_w = (const float*)d_in[9];
    const float* ff1_b = (const float*)d_in[10];
    const float* ff2_w = (const float*)d_in[11];
    const float* ff2_b = (const float*)d_in[12];
    const float* g2    = (const float*)d_in[13];
    const float* b2    = (const float*)d_in[14];
    float* outp = (float*)d_out;
    float* c_ws = (float*)d_ws;        // 2048 floats

    k1_scores<<<256, 256, 0, stream>>>(in_obs, Wk_w, Wk_b, wv_w, c_ws);
    k2_ffn<<<256, 256, 0, stream>>>(in_obs, c_ws, g1, b1,
                                    ff1_w, ff1_b, ff2_w, ff2_b, g2, b2, outp);
}

// Round 2
// 34.723 us; speedup vs baseline: 1.4010x; 1.4010x over previous
//
#include <hip/hip_runtime.h>

#define BB 16
#define NN 128
#define DD 128
#define LL 512
#define FFH 512
#define TANH1 0.76159415595576489f

struct alignas(16) f4arr { float v[4]; };

// ---------------------------------------------------------------------------
// K1: c[b,j] = sum_l tanh(in_obs[b,j,:]Wk[:,l] + Wk_b[l]) * wv_w[640+l]
//             + tanh(1) * wv_w[1152+j]
// grid 256 blocks (8 rows each), 256 threads   (~1 us, leave alone)
// ---------------------------------------------------------------------------
__global__ __launch_bounds__(256) void k1_scores(
    const float* __restrict__ in_obs,
    const float* __restrict__ Wk_w,
    const float* __restrict__ Wk_b,
    const float* __restrict__ wv_w,
    float* __restrict__ c_out)
{
    const int t = threadIdx.x;
    const int row0 = blockIdx.x * 8;          // global row = b*128 + j
    __shared__ float row_lds[8][128];
    __shared__ float red[8][4];

    const float* src = in_obs + row0 * DD;
    #pragma unroll
    for (int i = 0; i < 4; ++i) {
        int idx = t + i * 256;
        row_lds[idx >> 7][idx & 127] = src[idx];
    }
    __syncthreads();

    const int l0 = t, l1 = t + 256;
    float acc0[8], acc1[8];
    #pragma unroll
    for (int r = 0; r < 8; ++r) { acc0[r] = 0.f; acc1[r] = 0.f; }

    #pragma unroll 4
    for (int d = 0; d < 128; d += 4) {
        f4arr rbuf[8];
        #pragma unroll
        for (int r = 0; r < 8; ++r)
            rbuf[r] = *(const f4arr*)&row_lds[r][d];
        #pragma unroll
        for (int dd = 0; dd < 4; ++dd) {
            const float w0 = Wk_w[(d + dd) * LL + l0];
            const float w1 = Wk_w[(d + dd) * LL + l1];
            #pragma unroll
            for (int r = 0; r < 8; ++r) {
                acc0[r] += rbuf[r].v[dd] * w0;
                acc1[r] += rbuf[r].v[dd] * w1;
            }
        }
    }
    const float kb0 = Wk_b[l0], kb1 = Wk_b[l1];
    const float wv0 = wv_w[640 + l0], wv1 = wv_w[640 + l1];
    float v[8];
    #pragma unroll
    for (int r = 0; r < 8; ++r)
        v[r] = tanhf(acc0[r] + kb0) * wv0 + tanhf(acc1[r] + kb1) * wv1;
    #pragma unroll
    for (int off = 32; off > 0; off >>= 1) {
        #pragma unroll
        for (int r = 0; r < 8; ++r)
            v[r] += __shfl_down(v[r], off, 64);
    }
    const int wave = t >> 6, lane = t & 63;
    if (lane == 0) {
        #pragma unroll
        for (int r = 0; r < 8; ++r) red[r][wave] = v[r];
    }
    __syncthreads();
    if (t < 8) {
        const int row = row0 + t;
        const int j = row & (NN - 1);
        c_out[row] = red[t][0] + red[t][1] + red[t][2] + red[t][3]
                   + TANH1 * wv_w[1152 + j];
    }
}

// ---------------------------------------------------------------------------
// K2: 1024 threads/block, 256 blocks (8 rows of one batch each).
// softmax(c) -> attn vec -> LN1 -> FF1(relu, split-K over 2) ->
// FF2 (split-K over 8) -> LN2.
// 16 waves/block = 4 waves/SIMD for latency hiding; scratch LDS reused
// for attn-partials / FF1-partials / FF2-partials.
// ---------------------------------------------------------------------------
__global__ __launch_bounds__(1024) void k2_ffn(
    const float* __restrict__ in_obs,
    const float* __restrict__ c_in,
    const float* __restrict__ g1, const float* __restrict__ b1,
    const float* __restrict__ ff1_w, const float* __restrict__ ff1_b,
    const float* __restrict__ ff2_w, const float* __restrict__ ff2_b,
    const float* __restrict__ g2, const float* __restrict__ b2,
    float* __restrict__ out)
{
    const int t = threadIdx.x;
    const int b = blockIdx.x >> 4;
    const int j0 = (blockIdx.x & 15) * 8;
    const int wave = t >> 6, lane = t & 63;

    __shared__ float scratch[8192];      // 32 KB: ap[8][128] / ph[2][8][512] / ffp[8][8][128]
    __shared__ float h_lds[8][512];      // 16 KB
    __shared__ float res_lds[8][128];    //  4 KB
    __shared__ float wts[128];
    __shared__ float attn_v[128];
    __shared__ float sred;

    // ---- softmax over c[b,:] (q-side term cancels along softmax axis)
    const float* cb = c_in + b * NN;
    if (t < 64) {
        float m = fmaxf(cb[t], cb[t + 64]);
        #pragma unroll
        for (int off = 32; off > 0; off >>= 1)
            m = fmaxf(m, __shfl_xor(m, off, 64));
        if (t == 0) sred = m;
    }
    __syncthreads();
    const float M = sred;
    if (t < 128) wts[t] = __expf(cb[t] - M);
    __syncthreads();
    if (t < 64) {
        float s = wts[t] + wts[t + 64];
        #pragma unroll
        for (int off = 32; off > 0; off >>= 1)
            s += __shfl_xor(s, off, 64);
        if (t == 0) sred = s;
    }
    __syncthreads();
    const float Sinv = 1.f / sred;
    if (t < 128) wts[t] *= Sinv;
    __syncthreads();

    // ---- attn vector partials: grp g sums 16 j's for its d
    {
        const int d = t & 127, grp = t >> 7;
        const float* base = in_obs + (b * NN + grp * 16) * DD + d;
        float a = 0.f;
        #pragma unroll
        for (int j = 0; j < 16; ++j)
            a += wts[grp * 16 + j] * base[j * DD];
        scratch[grp * 128 + d] = a;
    }
    __syncthreads();
    if (t < 128) {
        float a = 0.f;
        #pragma unroll
        for (int g = 0; g < 8; ++g) a += scratch[g * 128 + t];
        attn_v[t] = a;
    }
    __syncthreads();

    // ---- residual + LN1 -> res_lds  (waves 0-7, one row each)
    if (wave < 8) {
        const int row = b * NN + j0 + wave;
        const float x0 = attn_v[lane] + in_obs[row * DD + lane];
        const float x1 = attn_v[lane + 64] + in_obs[row * DD + lane + 64];
        float s = x0 + x1;
        #pragma unroll
        for (int off = 32; off > 0; off >>= 1) s += __shfl_xor(s, off, 64);
        const float mu = s * (1.f / 128.f);
        const float d0 = x0 - mu, d1 = x1 - mu;
        float vs = d0 * d0 + d1 * d1;
        #pragma unroll
        for (int off = 32; off > 0; off >>= 1) vs += __shfl_xor(vs, off, 64);
        const float rstd = rsqrtf(vs * (1.f / 128.f) + 1e-5f);
        res_lds[wave][lane]      = d0 * rstd * g1[lane]      + b1[lane];
        res_lds[wave][lane + 64] = d1 * rstd * g1[lane + 64] + b1[lane + 64];
    }
    __syncthreads();

    // ---- FF1 partials: thread owns (col, d-half); ph[half][r][col]
    {
        const int col = t & 511, dhalf = t >> 9;
        const int dbase = dhalf * 64;
        float acc[8];
        #pragma unroll
        for (int r = 0; r < 8; ++r) acc[r] = 0.f;
        #pragma unroll 4
        for (int dc = 0; dc < 64; dc += 4) {
            const int d = dbase + dc;
            float w[4];
            #pragma unroll
            for (int k = 0; k < 4; ++k) w[k] = ff1_w[(d + k) * FFH + col];
            f4arr rb[8];
            #pragma unroll
            for (int r = 0; r < 8; ++r)
                rb[r] = *(const f4arr*)&res_lds[r][d];
            #pragma unroll
            for (int r = 0; r < 8; ++r)
                acc[r] += rb[r].v[0] * w[0] + rb[r].v[1] * w[1]
                        + rb[r].v[2] * w[2] + rb[r].v[3] * w[3];
        }
        #pragma unroll
        for (int r = 0; r < 8; ++r)
            scratch[(dhalf * 8 + r) * 512 + col] = acc[r];
    }
    __syncthreads();

    // ---- combine halves + bias + relu -> h_lds  (4 elements/thread, f4)
    {
        const int r = t >> 7, c0 = (t & 127) * 4;
        const f4arr p0 = *(const f4arr*)&scratch[r * 512 + c0];
        const f4arr p1 = *(const f4arr*)&scratch[4096 + r * 512 + c0];
        const f4arr bb = *(const f4arr*)&ff1_b[c0];
        f4arr h;
        #pragma unroll
        for (int k = 0; k < 4; ++k)
            h.v[k] = fmaxf(p0.v[k] + p1.v[k] + bb.v[k], 0.f);
        *(f4arr*)&h_lds[r][c0] = h;
    }
    __syncthreads();

    // ---- FF2 partials: thread owns (d, l-oct); ffp[oct][r][d]
    {
        const int d = t & 127, oct = t >> 7;
        const int lbase = oct * 64;
        float acc[8];
        #pragma unroll
        for (int r = 0; r < 8; ++r) acc[r] = 0.f;
        #pragma unroll 4
        for (int lc = 0; lc < 64; lc += 4) {
            const int l = lbase + lc;
            float w[4];
            #pragma unroll
            for (int k = 0; k < 4; ++k) w[k] = ff2_w[(l + k) * DD + d];
            f4arr hb[8];
            #pragma unroll
            for (int r = 0; r < 8; ++r)
                hb[r] = *(const f4arr*)&h_lds[r][l];
            #pragma unroll
            for (int r = 0; r < 8; ++r)
                acc[r] += hb[r].v[0] * w[0] + hb[r].v[1] * w[1]
                        + hb[r].v[2] * w[2] + hb[r].v[3] * w[3];
        }
        #pragma unroll
        for (int r = 0; r < 8; ++r)
            scratch[(oct * 8 + r) * 128 + d] = acc[r];
    }
    __syncthreads();

    // ---- combine octs + bias + residual + LN2 -> out (waves 0-7)
    if (wave < 8) {
        const int row = b * NN + j0 + wave;
        float f0 = ff2_b[lane]      + in_obs[row * DD + lane];
        float f1 = ff2_b[lane + 64] + in_obs[row * DD + lane + 64];
        #pragma unroll
        for (int o = 0; o < 8; ++o) {
            f0 += scratch[(o * 8 + wave) * 128 + lane];
            f1 += scratch[(o * 8 + wave) * 128 + lane + 64];
        }
        float s = f0 + f1;
        #pragma unroll
        for (int off = 32; off > 0; off >>= 1) s += __shfl_xor(s, off, 64);
        const float mu = s * (1.f / 128.f);
        const float d0 = f0 - mu, d1 = f1 - mu;
        float vs = d0 * d0 + d1 * d1;
        #pragma unroll
        for (int off = 32; off > 0; off >>= 1) vs += __shfl_xor(vs, off, 64);
        const float rstd = rsqrtf(vs * (1.f / 128.f) + 1e-5f);
        out[row * DD + lane]      = d0 * rstd * g2[lane]      + b2[lane];
        out[row * DD + lane + 64] = d1 * rstd * g2[lane + 64] + b2[lane + 64];
    }
}

extern "C" void kernel_launch(void* const* d_in, const int* in_sizes, int n_in,
                              void* d_out, int out_size, void* d_ws, size_t ws_size,
                              hipStream_t stream) {
    const float* in_obs = (const float*)d_in[0];
    // d_in[1] Wq_w, d_in[2] Wq_b, d_in[6] wv_b: dead (cancel in softmax)
    const float* Wk_w  = (const float*)d_in[3];
    const float* Wk_b  = (const float*)d_in[4];
    const float* wv_w  = (const float*)d_in[5];
    const float* g1    = (const float*)d_in[7];
    const float* b1    = (const float*)d_in[8];
    const float* ff1_w = (const float*)d_in[9];
    const float* ff1_b = (const float*)d_in[10];
    const float* ff2_w = (const float*)d_in[11];
    const float* ff2_b = (const float*)d_in[12];
    const float* g2    = (const float*)d_in[13];
    const float* b2    = (const float*)d_in[14];
    float* outp = (float*)d_out;
    float* c_ws = (float*)d_ws;        // 2048 floats

    k1_scores<<<256, 256, 0, stream>>>(in_obs, Wk_w, Wk_b, wv_w, c_ws);
    k2_ffn<<<256, 1024, 0, stream>>>(in_obs, c_ws, g1, b1,
                                     ff1_w, ff1_b, ff2_w, ff2_b, g2, b2, outp);
}

// Round 3
// 31.058 us; speedup vs baseline: 1.5664x; 1.1180x over previous
//
#include <hip/hip_runtime.h>

#define NN 128
#define DD 128
#define LL 512
#define FFH 512
#define TANH1 0.76159415595576489f

typedef __attribute__((ext_vector_type(8))) short bf16x8;
typedef __attribute__((ext_vector_type(4))) float f32x4;

struct alignas(16) f4arr { float v[4]; };

__device__ __forceinline__ unsigned short f2bf(float f) {
    union { float f; unsigned u; } v; v.f = f;
    return (unsigned short)((v.u + 0x7FFFu + ((v.u >> 16) & 1u)) >> 16);
}

// ---------------------------------------------------------------------------
// k0: weight re-layout into MFMA A-fragment order (bf16), into d_ws.
// A-frag for v_mfma_f32_16x16x32_bf16: lane l holds A[m=l&15][k=8*(l>>4)+j].
// FF1 swapped: A = W1^T (M=512 cols, K=128): elem = ff1_w[k*512 + m]
//   frag-group fg = mt*4 + ks  (mt 0..31, ks 0..3), k = ks*32+8*(l>>4)+j
// FF2 swapped: A = W2^T (M=128 cols, K=512): elem = ff2_w[k*128 + m]
//   fg = mt*16 + ks (mt 0..7, ks 0..15)
// Layout: Wf[(fg*64 + lane)*8 + j]  -> kernel reads one b128 per frag.
// ---------------------------------------------------------------------------
__global__ __launch_bounds__(256) void k0_prep(
    const float* __restrict__ ff1_w,
    const float* __restrict__ ff2_w,
    unsigned short* __restrict__ W1f,
    unsigned short* __restrict__ W2f)
{
    const int t = threadIdx.x;
    const int wave = t >> 6, lane = t & 63;
    const int l15 = lane & 15, l4 = lane >> 4;
    const int bi = blockIdx.x;
    const int fg = (bi & 31) * 4 + wave;

    unsigned short vals[8];
    unsigned short* dst;
    if (bi < 32) {
        const int ks = fg & 3, mt = fg >> 2;
        #pragma unroll
        for (int j = 0; j < 8; ++j)
            vals[j] = f2bf(ff1_w[(ks * 32 + l4 * 8 + j) * FFH + mt * 16 + l15]);
        dst = W1f;
    } else {
        const int ks = fg & 15, mt = fg >> 4;
        #pragma unroll
        for (int j = 0; j < 8; ++j)
            vals[j] = f2bf(ff2_w[(ks * 32 + l4 * 8 + j) * DD + mt * 16 + l15]);
        dst = W2f;
    }
    uint4 u;
    u.x = (unsigned)vals[0] | ((unsigned)vals[1] << 16);
    u.y = (unsigned)vals[2] | ((unsigned)vals[3] << 16);
    u.z = (unsigned)vals[4] | ((unsigned)vals[5] << 16);
    u.w = (unsigned)vals[6] | ((unsigned)vals[7] << 16);
    *(uint4*)&dst[(fg * 64 + lane) * 8] = u;
}

// ---------------------------------------------------------------------------
// k1: c[b,j] (fp32, unchanged — ~1 us)
// ---------------------------------------------------------------------------
__global__ __launch_bounds__(256) void k1_scores(
    const float* __restrict__ in_obs,
    const float* __restrict__ Wk_w,
    const float* __restrict__ Wk_b,
    const float* __restrict__ wv_w,
    float* __restrict__ c_out)
{
    const int t = threadIdx.x;
    const int row0 = blockIdx.x * 8;
    __shared__ float row_lds[8][128];
    __shared__ float red[8][4];

    const float* src = in_obs + row0 * DD;
    #pragma unroll
    for (int i = 0; i < 4; ++i) {
        int idx = t + i * 256;
        row_lds[idx >> 7][idx & 127] = src[idx];
    }
    __syncthreads();

    const int l0 = t, l1 = t + 256;
    float acc0[8], acc1[8];
    #pragma unroll
    for (int r = 0; r < 8; ++r) { acc0[r] = 0.f; acc1[r] = 0.f; }

    #pragma unroll 4
    for (int d = 0; d < 128; d += 4) {
        f4arr rbuf[8];
        #pragma unroll
        for (int r = 0; r < 8; ++r)
            rbuf[r] = *(const f4arr*)&row_lds[r][d];
        #pragma unroll
        for (int dd = 0; dd < 4; ++dd) {
            const float w0 = Wk_w[(d + dd) * LL + l0];
            const float w1 = Wk_w[(d + dd) * LL + l1];
            #pragma unroll
            for (int r = 0; r < 8; ++r) {
                acc0[r] += rbuf[r].v[dd] * w0;
                acc1[r] += rbuf[r].v[dd] * w1;
            }
        }
    }
    const float kb0 = Wk_b[l0], kb1 = Wk_b[l1];
    const float wv0 = wv_w[640 + l0], wv1 = wv_w[640 + l1];
    float v[8];
    #pragma unroll
    for (int r = 0; r < 8; ++r)
        v[r] = tanhf(acc0[r] + kb0) * wv0 + tanhf(acc1[r] + kb1) * wv1;
    #pragma unroll
    for (int off = 32; off > 0; off >>= 1) {
        #pragma unroll
        for (int r = 0; r < 8; ++r)
            v[r] += __shfl_down(v[r], off, 64);
    }
    const int wave = t >> 6, lane = t & 63;
    if (lane == 0) {
        #pragma unroll
        for (int r = 0; r < 8; ++r) red[r][wave] = v[r];
    }
    __syncthreads();
    if (t < 8) {
        const int row = row0 + t;
        const int j = row & (NN - 1);
        c_out[row] = red[t][0] + red[t][1] + red[t][2] + red[t][3]
                   + TANH1 * wv_w[1152 + j];
    }
}

// ---------------------------------------------------------------------------
// k2: 256 blocks x 512 thr (8 waves). 8 real rows padded to M=16.
// softmax -> attn vec -> LN1 (fp32) -> FF1 (MFMA, swapped) -> FF2 (MFMA,
// swapped) -> LN2. Activation tiles in LDS bf16 row-major, XOR-swizzled.
// ---------------------------------------------------------------------------
__global__ __launch_bounds__(512) void k2_ffn(
    const float* __restrict__ in_obs,
    const float* __restrict__ c_in,
    const unsigned short* __restrict__ W1f,
    const unsigned short* __restrict__ W2f,
    const float* __restrict__ g1, const float* __restrict__ b1,
    const float* __restrict__ ff1_b,
    const float* __restrict__ ff2_b,
    const float* __restrict__ g2, const float* __restrict__ b2,
    float* __restrict__ out)
{
    const int t = threadIdx.x;
    const int b = blockIdx.x >> 4;
    const int j0 = (blockIdx.x & 15) * 8;
    const int wave = t >> 6, lane = t & 63;
    const int l15 = lane & 15, l4 = lane >> 4;

    __shared__ alignas(16) unsigned short res_lds[16 * 128]; // bf16, row stride 256B, swizzled
    __shared__ alignas(16) unsigned short h_lds[16 * 512];   // bf16, row stride 1024B, swizzled
    __shared__ alignas(16) float o2_lds[16 * 128];           // f32, row stride 512B, swizzled
    __shared__ float part[4][128];
    __shared__ float wts[128];
    __shared__ float attn_v[128];
    __shared__ float sred;

    // ---- softmax over c[b,:] (q-side term cancels along softmax axis)
    const float* cb = c_in + b * NN;
    if (t < 64) {
        float m = fmaxf(cb[t], cb[t + 64]);
        #pragma unroll
        for (int off = 32; off > 0; off >>= 1)
            m = fmaxf(m, __shfl_xor(m, off, 64));
        if (t == 0) sred = m;
    }
    __syncthreads();
    const float M = sred;
    if (t < 128) wts[t] = __expf(cb[t] - M);
    __syncthreads();
    if (t < 64) {
        float s = wts[t] + wts[t + 64];
        #pragma unroll
        for (int off = 32; off > 0; off >>= 1)
            s += __shfl_xor(s, off, 64);
        if (t == 0) sred = s;
    }
    __syncthreads();
    const float Sinv = 1.f / sred;
    if (t < 128) wts[t] *= Sinv;
    __syncthreads();

    // ---- attn vector partials (4 j-groups of 32)
    {
        const int d = t & 127, grp = t >> 7;
        const float* base = in_obs + (b * NN + grp * 32) * DD + d;
        float a = 0.f;
        #pragma unroll 4
        for (int j = 0; j < 32; ++j)
            a += wts[grp * 32 + j] * base[j * DD];
        part[grp][d] = a;
    }
    __syncthreads();
    if (t < 128)
        attn_v[t] = part[0][t] + part[1][t] + part[2][t] + part[3][t];
    __syncthreads();

    // ---- residual + LN1 -> res_lds bf16 (wave w = row w; rows 8-15 zeroed)
    {
        const int r = wave;
        const int row = b * NN + j0 + r;
        const int c0 = lane * 2;
        const float2 xo = *(const float2*)&in_obs[row * DD + c0];
        const float x0 = attn_v[c0] + xo.x;
        const float x1 = attn_v[c0 + 1] + xo.y;
        float s = x0 + x1;
        #pragma unroll
        for (int off = 32; off > 0; off >>= 1) s += __shfl_xor(s, off, 64);
        const float mu = s * (1.f / 128.f);
        const float d0 = x0 - mu, d1 = x1 - mu;
        float vs = d0 * d0 + d1 * d1;
        #pragma unroll
        for (int off = 32; off > 0; off >>= 1) vs += __shfl_xor(vs, off, 64);
        const float rstd = rsqrtf(vs * (1.f / 128.f) + 1e-5f);
        const float2 gv = *(const float2*)&g1[c0];
        const float2 bv = *(const float2*)&b1[c0];
        const float r0 = d0 * rstd * gv.x + bv.x;
        const float r1 = d1 * rstd * gv.y + bv.y;
        const unsigned pk = (unsigned)f2bf(r0) | ((unsigned)f2bf(r1) << 16);
        const int swz = (lane * 4) ^ ((r & 7) << 4);
        *(unsigned*)((char*)res_lds + r * 256 + swz) = pk;
        *(unsigned*)((char*)res_lds + (r + 8) * 256 + swz) = 0u;  // pad rows
    }
    __syncthreads();

    // ---- FF1 swapped: D[c][m] = sum_k W1^T[c][k] * res[m][k]
    //      B-frag: lane l = res row l15, k = ks*32+8*l4+j (contiguous b128)
    {
        bf16x8 bfrag[4];
        #pragma unroll
        for (int ks = 0; ks < 4; ++ks) {
            const int off = l15 * 256 + ((ks * 64 + l4 * 16) ^ ((l15 & 7) << 4));
            bfrag[ks] = *(const bf16x8*)((const char*)res_lds + off);
        }
        #pragma unroll
        for (int i = 0; i < 4; ++i) {
            const int mt = wave * 4 + i;
            f32x4 acc = {0.f, 0.f, 0.f, 0.f};
            #pragma unroll
            for (int ks = 0; ks < 4; ++ks) {
                const bf16x8 afrag = *(const bf16x8*)(W1f + ((mt * 4 + ks) * 64 + lane) * 8);
                acc = __builtin_amdgcn_mfma_f32_16x16x32_bf16(afrag, bfrag[ks], acc, 0, 0, 0);
            }
            // D: H col c = mt*16 + l4*4 + r, row m = l15
            const f4arr bias = *(const f4arr*)&ff1_b[mt * 16 + l4 * 4];
            const float h0 = fmaxf(acc[0] + bias.v[0], 0.f);
            const float h1 = fmaxf(acc[1] + bias.v[1], 0.f);
            const float h2 = fmaxf(acc[2] + bias.v[2], 0.f);
            const float h3 = fmaxf(acc[3] + bias.v[3], 0.f);
            uint2 pk;
            pk.x = (unsigned)f2bf(h0) | ((unsigned)f2bf(h1) << 16);
            pk.y = (unsigned)f2bf(h2) | ((unsigned)f2bf(h3) << 16);
            const int off = l15 * 1024 + ((mt * 32 + l4 * 8) ^ ((l15 & 7) << 4));
            *(uint2*)((char*)h_lds + off) = pk;
        }
    }
    __syncthreads();

    // ---- FF2 swapped: D[n][m] = sum_k W2^T[n][k] * H[m][k]; wave = n-tile
    {
        f32x4 acc = {0.f, 0.f, 0.f, 0.f};
        #pragma unroll
        for (int ks = 0; ks < 16; ++ks) {
            const int off = l15 * 1024 + ((ks * 64 + l4 * 16) ^ ((l15 & 7) << 4));
            const bf16x8 bfrag = *(const bf16x8*)((const char*)h_lds + off);
            const bf16x8 afrag = *(const bf16x8*)(W2f + ((wave * 16 + ks) * 64 + lane) * 8);
            acc = __builtin_amdgcn_mfma_f32_16x16x32_bf16(afrag, bfrag, acc, 0, 0, 0);
        }
        // D: out col n = wave*16 + l4*4 + r, row m = l15
        const int off = l15 * 512 + ((wave * 64 + l4 * 16) ^ ((l15 & 7) << 4));
        *(f32x4*)((char*)o2_lds + off) = acc;
    }
    __syncthreads();

    // ---- bias + residual + LN2 -> out (wave w = row w)
    {
        const int r = wave;
        const int row = b * NN + j0 + r;
        const int c0 = lane * 2;
        const int off = r * 512 + ((lane * 8) ^ ((r & 7) << 4));
        const float2 o2 = *(const float2*)((char*)o2_lds + off);
        const float2 fb = *(const float2*)&ff2_b[c0];
        const float2 xo = *(const float2*)&in_obs[row * DD + c0];
        const float f0 = o2.x + fb.x + xo.x;
        const float f1 = o2.y + fb.y + xo.y;
        float s = f0 + f1;
        #pragma unroll
        for (int off2 = 32; off2 > 0; off2 >>= 1) s += __shfl_xor(s, off2, 64);
        const float mu = s * (1.f / 128.f);
        const float d0 = f0 - mu, d1 = f1 - mu;
        float vs = d0 * d0 + d1 * d1;
        #pragma unroll
        for (int off2 = 32; off2 > 0; off2 >>= 1) vs += __shfl_xor(vs, off2, 64);
        const float rstd = rsqrtf(vs * (1.f / 128.f) + 1e-5f);
        const float2 gv = *(const float2*)&g2[c0];
        const float2 bv = *(const float2*)&b2[c0];
        float2 o;
        o.x = d0 * rstd * gv.x + bv.x;
        o.y = d1 * rstd * gv.y + bv.y;
        *(float2*)&out[row * DD + c0] = o;
    }
}

extern "C" void kernel_launch(void* const* d_in, const int* in_sizes, int n_in,
                              void* d_out, int out_size, void* d_ws, size_t ws_size,
                              hipStream_t stream) {
    const float* in_obs = (const float*)d_in[0];
    // d_in[1] Wq_w, d_in[2] Wq_b, d_in[6] wv_b: dead (cancel in softmax)
    const float* Wk_w  = (const float*)d_in[3];
    const float* Wk_b  = (const float*)d_in[4];
    const float* wv_w  = (const float*)d_in[5];
    const float* g1    = (const float*)d_in[7];
    const float* b1    = (const float*)d_in[8];
    const float* ff1_w = (const float*)d_in[9];
    const float* ff1_b = (const float*)d_in[10];
    const float* ff2_w = (const float*)d_in[11];
    const float* ff2_b = (const float*)d_in[12];
    const float* g2    = (const float*)d_in[13];
    const float* b2    = (const float*)d_in[14];
    float* outp = (float*)d_out;

    unsigned short* W1f = (unsigned short*)d_ws;            // 128 KB
    unsigned short* W2f = W1f + 65536;                      // 128 KB
    float* c_ws = (float*)((char*)d_ws + 262144);           // 8 KB

    k0_prep<<<64, 256, 0, stream>>>(ff1_w, ff2_w, W1f, W2f);
    k1_scores<<<256, 256, 0, stream>>>(in_obs, Wk_w, Wk_b, wv_w, c_ws);
    k2_ffn<<<256, 512, 0, stream>>>(in_obs, c_ws, W1f, W2f, g1, b1,
                                    ff1_b, ff2_b, g2, b2, outp);
}

// Round 4
// 26.985 us; speedup vs baseline: 1.8028x; 1.1509x over previous
//
#include <hip/hip_runtime.h>

#define NN 128
#define DD 128
#define LL 512
#define FFH 512
#define TANH1 0.76159415595576489f

typedef __attribute__((ext_vector_type(8))) short bf16x8;
typedef __attribute__((ext_vector_type(4))) float f32x4;

struct alignas(16) f4arr { float v[4]; };

__device__ __forceinline__ unsigned short f2bf(float f) {
    union { float f; unsigned u; } v; v.f = f;
    return (unsigned short)((v.u + 0x7FFFu + ((v.u >> 16) & 1u)) >> 16);
}

// ---------------------------------------------------------------------------
// kA: blocks 0-255  -> scores c[b,j] (fp32), 8 rows/block
//     blocks 256-319 -> ff1_w/ff2_w -> bf16 MFMA A-fragment relayout
// (independent work fused into one launch to cut a serial graph stage)
// ---------------------------------------------------------------------------
__global__ __launch_bounds__(256) void kA(
    const float* __restrict__ in_obs,
    const float* __restrict__ Wk_w,
    const float* __restrict__ Wk_b,
    const float* __restrict__ wv_w,
    const float* __restrict__ ff1_w,
    const float* __restrict__ ff2_w,
    float* __restrict__ c_out,
    unsigned short* __restrict__ W1f,
    unsigned short* __restrict__ W2f)
{
    const int t = threadIdx.x;
    const int wave = t >> 6, lane = t & 63;
    __shared__ float row_lds[8][128];
    __shared__ float red[8][4];

    if (blockIdx.x >= 256) {
        // ---- weight fragment prep
        const int bi = blockIdx.x - 256;
        const int l15 = lane & 15, l4 = lane >> 4;
        const int fg = (bi & 31) * 4 + wave;
        unsigned short vals[8];
        unsigned short* dst;
        if (bi < 32) {
            const int ks = fg & 3, mt = fg >> 2;
            #pragma unroll
            for (int j = 0; j < 8; ++j)
                vals[j] = f2bf(ff1_w[(ks * 32 + l4 * 8 + j) * FFH + mt * 16 + l15]);
            dst = W1f;
        } else {
            const int ks = fg & 15, mt = fg >> 4;
            #pragma unroll
            for (int j = 0; j < 8; ++j)
                vals[j] = f2bf(ff2_w[(ks * 32 + l4 * 8 + j) * DD + mt * 16 + l15]);
            dst = W2f;
        }
        uint4 u;
        u.x = (unsigned)vals[0] | ((unsigned)vals[1] << 16);
        u.y = (unsigned)vals[2] | ((unsigned)vals[3] << 16);
        u.z = (unsigned)vals[4] | ((unsigned)vals[5] << 16);
        u.w = (unsigned)vals[6] | ((unsigned)vals[7] << 16);
        *(uint4*)&dst[(fg * 64 + lane) * 8] = u;
        return;
    }

    // ---- scores
    const int row0 = blockIdx.x * 8;
    const float* src = in_obs + row0 * DD;
    #pragma unroll
    for (int i = 0; i < 4; ++i) {
        int idx = t + i * 256;
        row_lds[idx >> 7][idx & 127] = src[idx];
    }
    __syncthreads();

    const int l0 = t, l1 = t + 256;
    float acc0[8], acc1[8];
    #pragma unroll
    for (int r = 0; r < 8; ++r) { acc0[r] = 0.f; acc1[r] = 0.f; }

    #pragma unroll 4
    for (int d = 0; d < 128; d += 4) {
        f4arr rbuf[8];
        #pragma unroll
        for (int r = 0; r < 8; ++r)
            rbuf[r] = *(const f4arr*)&row_lds[r][d];
        #pragma unroll
        for (int dd = 0; dd < 4; ++dd) {
            const float w0 = Wk_w[(d + dd) * LL + l0];
            const float w1 = Wk_w[(d + dd) * LL + l1];
            #pragma unroll
            for (int r = 0; r < 8; ++r) {
                acc0[r] += rbuf[r].v[dd] * w0;
                acc1[r] += rbuf[r].v[dd] * w1;
            }
        }
    }
    const float kb0 = Wk_b[l0], kb1 = Wk_b[l1];
    const float wv0 = wv_w[640 + l0], wv1 = wv_w[640 + l1];
    float v[8];
    #pragma unroll
    for (int r = 0; r < 8; ++r)
        v[r] = tanhf(acc0[r] + kb0) * wv0 + tanhf(acc1[r] + kb1) * wv1;
    #pragma unroll
    for (int off = 32; off > 0; off >>= 1) {
        #pragma unroll
        for (int r = 0; r < 8; ++r)
            v[r] += __shfl_down(v[r], off, 64);
    }
    if (lane == 0) {
        #pragma unroll
        for (int r = 0; r < 8; ++r) red[r][wave] = v[r];
    }
    __syncthreads();
    if (t < 8) {
        const int row = row0 + t;
        const int j = row & (NN - 1);
        c_out[row] = red[t][0] + red[t][1] + red[t][2] + red[t][3]
                   + TANH1 * wv_w[1152 + j];
    }
}

// ---------------------------------------------------------------------------
// kB: 256 blocks x 1024 thr (16 waves = 4/SIMD), 8 rows of one batch each.
// In-register softmax (0 barriers) -> attn partials -> B1 -> LN1 -> B2 ->
// FF1 MFMA (mt = wave*2+i) -> B3 -> FF2 MFMA (split-K over wave pairs) ->
// B4 -> LN2. Weight fragments prefetched to registers at kernel top.
// ---------------------------------------------------------------------------
__global__ __launch_bounds__(1024) void kB(
    const float* __restrict__ in_obs,
    const float* __restrict__ c_in,
    const unsigned short* __restrict__ W1f,
    const unsigned short* __restrict__ W2f,
    const float* __restrict__ g1, const float* __restrict__ b1,
    const float* __restrict__ ff1_b,
    const float* __restrict__ ff2_b,
    const float* __restrict__ g2, const float* __restrict__ b2,
    float* __restrict__ out)
{
    const int t = threadIdx.x;
    const int b = blockIdx.x >> 4;
    const int j0 = (blockIdx.x & 15) * 8;
    const int wave = t >> 6, lane = t & 63;
    const int l15 = lane & 15, l4 = lane >> 4;

    __shared__ alignas(16) unsigned short res_lds[16 * 128]; // 4 KB swizzled bf16
    __shared__ alignas(16) unsigned short h_lds[16 * 512];   // 16 KB
    __shared__ alignas(16) float o2p[2][2048];               // 16 KB (FF2 k-half partials)
    __shared__ float part[8][128];                           // 4 KB attn partials

    // ---- weight fragment prefetch (latency hides under softmax/attn/LN1)
    bf16x8 a1[2][4];
    #pragma unroll
    for (int i = 0; i < 2; ++i)
        #pragma unroll
        for (int ks = 0; ks < 4; ++ks)
            a1[i][ks] = *(const bf16x8*)(W1f + (((wave * 2 + i) * 4 + ks) * 64 + lane) * 8);
    bf16x8 a2[8];
    {
        const int n = wave & 7, kh = wave >> 3;
        #pragma unroll
        for (int k2 = 0; k2 < 8; ++k2)
            a2[k2] = *(const bf16x8*)(W2f + ((n * 16 + kh * 8 + k2) * 64 + lane) * 8);
    }

    // ---- per-row constants for LN phases (waves 0-7), prefetched once
    const int r = wave & 7;
    const int row = b * NN + j0 + r;
    const int c0i = lane * 2;
    float2 xo, g1v, b1v, g2v, b2v, f2bv;
    if (wave < 8) {
        xo   = *(const float2*)&in_obs[row * DD + c0i];
        g1v  = *(const float2*)&g1[c0i];  b1v = *(const float2*)&b1[c0i];
        g2v  = *(const float2*)&g2[c0i];  b2v = *(const float2*)&b2[c0i];
        f2bv = *(const float2*)&ff2_b[c0i];
    }

    // ---- softmax fully in registers (each wave redundantly; q-side cancels)
    const float* cb = c_in + b * NN;
    float c0 = cb[lane], c1 = cb[lane + 64];
    float mx = fmaxf(c0, c1);
    #pragma unroll
    for (int off = 32; off > 0; off >>= 1) mx = fmaxf(mx, __shfl_xor(mx, off, 64));
    float e0 = __expf(c0 - mx), e1 = __expf(c1 - mx);
    float sm = e0 + e1;
    #pragma unroll
    for (int off = 32; off > 0; off >>= 1) sm += __shfl_xor(sm, off, 64);
    const float inv = 1.f / sm;
    e0 *= inv; e1 *= inv;

    // ---- attn partials: wave w sums 16 j's for d-half (w&1); grp = w>>1
    {
        const int grp = wave >> 1, d = (wave & 1) * 64 + lane;
        const float* base = in_obs + (b * NN + grp * 16) * DD + d;
        float acc = 0.f;
        #pragma unroll
        for (int jj = 0; jj < 16; ++jj) {
            const int j = grp * 16 + jj;          // compile-time after unroll
            const float wj = (grp < 4) ? __shfl(e0, j & 63, 64)
                                       : __shfl(e1, j & 63, 64);
            acc += wj * base[jj * DD];
        }
        part[grp][d] = acc;
    }
    __syncthreads();                              // B1

    // ---- residual + LN1 -> res_lds bf16 (waves 0-7; pad rows 8-15 zeroed)
    if (wave < 8) {
        float x0 = xo.x, x1 = xo.y;
        #pragma unroll
        for (int g = 0; g < 8; ++g) { x0 += part[g][c0i]; x1 += part[g][c0i + 1]; }
        float s = x0 + x1;
        #pragma unroll
        for (int off = 32; off > 0; off >>= 1) s += __shfl_xor(s, off, 64);
        const float mu = s * (1.f / 128.f);
        const float d0 = x0 - mu, d1 = x1 - mu;
        float vs = d0 * d0 + d1 * d1;
        #pragma unroll
        for (int off = 32; off > 0; off >>= 1) vs += __shfl_xor(vs, off, 64);
        const float rstd = rsqrtf(vs * (1.f / 128.f) + 1e-5f);
        const float r0 = d0 * rstd * g1v.x + b1v.x;
        const float r1 = d1 * rstd * g1v.y + b1v.y;
        const unsigned pk = (unsigned)f2bf(r0) | ((unsigned)f2bf(r1) << 16);
        const int swz = (lane * 4) ^ ((r & 7) << 4);
        *(unsigned*)((char*)res_lds + r * 256 + swz) = pk;
        *(unsigned*)((char*)res_lds + (r + 8) * 256 + swz) = 0u;
    }
    __syncthreads();                              // B2

    // ---- FF1 swapped GEMM: wave does mt = wave*2 + {0,1}
    {
        bf16x8 bfrag[4];
        #pragma unroll
        for (int ks = 0; ks < 4; ++ks) {
            const int off = l15 * 256 + ((ks * 64 + l4 * 16) ^ ((l15 & 7) << 4));
            bfrag[ks] = *(const bf16x8*)((const char*)res_lds + off);
        }
        #pragma unroll
        for (int i = 0; i < 2; ++i) {
            const int mt = wave * 2 + i;
            f32x4 acc = {0.f, 0.f, 0.f, 0.f};
            #pragma unroll
            for (int ks = 0; ks < 4; ++ks)
                acc = __builtin_amdgcn_mfma_f32_16x16x32_bf16(a1[i][ks], bfrag[ks], acc, 0, 0, 0);
            const f4arr bias = *(const f4arr*)&ff1_b[mt * 16 + l4 * 4];
            uint2 pk;
            pk.x = (unsigned)f2bf(fmaxf(acc[0] + bias.v[0], 0.f))
                 | ((unsigned)f2bf(fmaxf(acc[1] + bias.v[1], 0.f)) << 16);
            pk.y = (unsigned)f2bf(fmaxf(acc[2] + bias.v[2], 0.f))
                 | ((unsigned)f2bf(fmaxf(acc[3] + bias.v[3], 0.f)) << 16);
            const int off = l15 * 1024 + ((mt * 32 + l4 * 8) ^ ((l15 & 7) << 4));
            *(uint2*)((char*)h_lds + off) = pk;
        }
    }
    __syncthreads();                              // B3

    // ---- FF2 swapped GEMM: wave (n = wave&7, k-half = wave>>3), 8 MFMA
    {
        const int n = wave & 7, kh = wave >> 3;
        f32x4 acc = {0.f, 0.f, 0.f, 0.f};
        #pragma unroll
        for (int k2 = 0; k2 < 8; ++k2) {
            const int ks = kh * 8 + k2;
            const int off = l15 * 1024 + ((ks * 64 + l4 * 16) ^ ((l15 & 7) << 4));
            const bf16x8 bfrag = *(const bf16x8*)((const char*)h_lds + off);
            acc = __builtin_amdgcn_mfma_f32_16x16x32_bf16(a2[k2], bfrag, acc, 0, 0, 0);
        }
        const int off = l15 * 512 + ((n * 64 + l4 * 16) ^ ((l15 & 7) << 4));
        *(f32x4*)((char*)o2p[kh] + off) = acc;
    }
    __syncthreads();                              // B4

    // ---- combine k-halves + bias + residual + LN2 -> out (waves 0-7)
    if (wave < 8) {
        const int off = r * 512 + ((lane * 8) ^ ((r & 7) << 4));
        const float2 p0 = *(const float2*)((char*)o2p[0] + off);
        const float2 p1 = *(const float2*)((char*)o2p[1] + off);
        const float f0 = p0.x + p1.x + f2bv.x + xo.x;
        const float f1 = p0.y + p1.y + f2bv.y + xo.y;
        float s = f0 + f1;
        #pragma unroll
        for (int off2 = 32; off2 > 0; off2 >>= 1) s += __shfl_xor(s, off2, 64);
        const float mu = s * (1.f / 128.f);
        const float d0 = f0 - mu, d1 = f1 - mu;
        float vs = d0 * d0 + d1 * d1;
        #pragma unroll
        for (int off2 = 32; off2 > 0; off2 >>= 1) vs += __shfl_xor(vs, off2, 64);
        const float rstd = rsqrtf(vs * (1.f / 128.f) + 1e-5f);
        float2 o;
        o.x = d0 * rstd * g2v.x + b2v.x;
        o.y = d1 * rstd * g2v.y + b2v.y;
        *(float2*)&out[row * DD + c0i] = o;
    }
}

extern "C" void kernel_launch(void* const* d_in, const int* in_sizes, int n_in,
                              void* d_out, int out_size, void* d_ws, size_t ws_size,
                              hipStream_t stream) {
    const float* in_obs = (const float*)d_in[0];
    // d_in[1] Wq_w, d_in[2] Wq_b, d_in[6] wv_b: dead (cancel in softmax)
    const float* Wk_w  = (const float*)d_in[3];
    const float* Wk_b  = (const float*)d_in[4];
    const float* wv_w  = (const float*)d_in[5];
    const float* g1    = (const float*)d_in[7];
    const float* b1    = (const float*)d_in[8];
    const float* ff1_w = (const float*)d_in[9];
    const float* ff1_b = (const float*)d_in[10];
    const float* ff2_w = (const float*)d_in[11];
    const float* ff2_b = (const float*)d_in[12];
    const float* g2    = (const float*)d_in[13];
    const float* b2    = (const float*)d_in[14];
    float* outp = (float*)d_out;

    unsigned short* W1f = (unsigned short*)d_ws;            // 128 KB
    unsigned short* W2f = W1f + 65536;                      // 128 KB
    float* c_ws = (float*)((char*)d_ws + 262144);           // 8 KB

    kA<<<320, 256, 0, stream>>>(in_obs, Wk_w, Wk_b, wv_w, ff1_w, ff2_w,
                                c_ws, W1f, W2f);
    kB<<<256, 1024, 0, stream>>>(in_obs, c_ws, W1f, W2f, g1, b1,
                                 ff1_b, ff2_b, g2, b2, outp);
}